// Round 1
// baseline (1437.775 us; speedup 1.0000x reference)
//
#include <hip/hip_runtime.h>
#include <math.h>

#define T_TOK 1024
#define H_DIM 2048
#define I_DIM 1024
#define E_NUM 32
#define G_NUM 8
#define EPG (E_NUM / G_NUM)
#define TOPK_GROUP 4
#define TOP_K 8
#define ROUTED_SCALE 2.5f

typedef __attribute__((ext_vector_type(8))) short bf16x8;
typedef __attribute__((ext_vector_type(4))) float f32x4;

__device__ __forceinline__ unsigned short f2bf(float f) {
    union { float f; unsigned u; } v; v.f = f;
    unsigned r = v.u + 0x7fffu + ((v.u >> 16) & 1u);   // RNE
    return (unsigned short)(r >> 16);
}

// ---------------- Router: fp32 logits, sigmoid, group-limited top-k ----------------
__global__ __launch_bounds__(256) void router_kernel(
    const float* __restrict__ x, const float* __restrict__ gate_w,
    const float* __restrict__ bias, int* __restrict__ cnt,
    int* __restrict__ tok_list, float* __restrict__ w_list)
{
    __shared__ float xs[H_DIM];
    __shared__ float part[E_NUM][8];
    __shared__ float scores[E_NUM];
    const int t = blockIdx.x;
    const int tid = threadIdx.x;

    const float4* xv = (const float4*)(x + (size_t)t * H_DIM);
    float4* xsv = (float4*)xs;
    for (int i = tid; i < H_DIM / 4; i += 256) xsv[i] = xv[i];
    __syncthreads();

    const int e = tid >> 3;      // 32 experts
    const int c = tid & 7;       // 8 lanes per expert
    const float4* gw4 = (const float4*)(gate_w + (size_t)e * H_DIM);
    const float4* xs4 = (const float4*)xs;
    float s = 0.f;
    #pragma unroll 8
    for (int j = 0; j < 64; j++) {
        float4 a = xs4[j * 8 + c];
        float4 b = gw4[j * 8 + c];
        s += a.x * b.x + a.y * b.y + a.z * b.z + a.w * b.w;
    }
    part[e][c] = s;
    __syncthreads();
    if (tid < E_NUM) {
        float l = 0.f;
        #pragma unroll
        for (int i = 0; i < 8; i++) l += part[tid][i];
        scores[tid] = 1.f / (1.f + expf(-l));
    }
    __syncthreads();
    if (tid == 0) {
        float sr[E_NUM];
        for (int i = 0; i < E_NUM; i++) sr[i] = scores[i] + bias[i];
        // group scores = top-2 sum within each group of EPG experts
        float gs[G_NUM];
        for (int g = 0; g < G_NUM; g++) {
            float m1 = -INFINITY, m2 = -INFINITY;
            for (int j = 0; j < EPG; j++) {
                float v = sr[g * EPG + j];
                if (v > m1) { m2 = m1; m1 = v; } else if (v > m2) { m2 = v; }
            }
            gs[g] = m1 + m2;
        }
        // top TOPK_GROUP groups (strict-greater argmax == jax tie-break by lowest idx)
        bool gmask[G_NUM];
        for (int g = 0; g < G_NUM; g++) gmask[g] = false;
        for (int k = 0; k < TOPK_GROUP; k++) {
            int bi = -1; float bv = -INFINITY;
            for (int g = 0; g < G_NUM; g++)
                if (!gmask[g] && gs[g] > bv) { bv = gs[g]; bi = g; }
            gmask[bi] = true;
        }
        // top TOP_K experts among unmasked groups
        bool esel[E_NUM];
        for (int i = 0; i < E_NUM; i++) esel[i] = false;
        int ids[TOP_K]; float wv[TOP_K]; float wsum = 0.f;
        for (int k = 0; k < TOP_K; k++) {
            int bi = -1; float bv = -INFINITY;
            for (int i = 0; i < E_NUM; i++) {
                if (esel[i] || !gmask[i / EPG]) continue;
                if (sr[i] > bv) { bv = sr[i]; bi = i; }
            }
            esel[bi] = true; ids[k] = bi;
            wv[k] = scores[bi]; wsum += wv[k];
        }
        const float scale = ROUTED_SCALE / (wsum + 1e-20f);
        for (int k = 0; k < TOP_K; k++) {
            int ei = ids[k];
            int slot = atomicAdd(&cnt[ei], 1);
            tok_list[ei * T_TOK + slot] = t;
            w_list[ei * T_TOK + slot] = wv[k] * scale;
        }
    }
}

// ---------------- x -> bf16 ----------------
__global__ __launch_bounds__(256) void cvt_kernel(const float* __restrict__ x,
                                                  unsigned short* __restrict__ xb)
{
    int i = blockIdx.x * 256 + threadIdx.x;   // over float4 units, exact grid
    float4 v = ((const float4*)x)[i];
    ushort4 o;
    o.x = f2bf(v.x); o.y = f2bf(v.y); o.z = f2bf(v.z); o.w = f2bf(v.w);
    ((ushort4*)xb)[i] = o;
}

// ---------------- Grouped gate_up GEMM + SiLU*u epilogue ----------------
// grid: (16 ntiles, 33 experts * 8 mtiles). Block tile 128x128, BK=64.
// GEMM cols 0..63  -> g features [nb*64, nb*64+64) (wgu rows nb*64 + r)
// GEMM cols 64..127-> u features (wgu rows I + nb*64 + r)
__global__ __launch_bounds__(256, 2) void gate_up_kernel(
    const unsigned short* __restrict__ xb, const float* __restrict__ w_gate_up,
    const float* __restrict__ shared_gate_up, const int* __restrict__ cnt,
    const int* __restrict__ tok_list, unsigned short* __restrict__ act)
{
    __shared__ unsigned short As[128 * 72];
    __shared__ unsigned short Bs[128 * 72];
    __shared__ int tokS[128];

    const int nb = blockIdx.x;
    const int ey = blockIdx.y;
    const int e  = ey >> 3;
    const int m0 = (ey & 7) * 128;

    int n_e, rowbase;
    const float* Bp;
    if (e == E_NUM) { n_e = T_TOK; rowbase = 8192 + m0; Bp = shared_gate_up; }
    else {
        n_e = cnt[e];
        int off = 0;
        for (int i = 0; i < e; i++) off += cnt[i];
        rowbase = off + m0;
        Bp = w_gate_up + (size_t)e * (2 * I_DIM) * H_DIM;
    }
    if (m0 >= n_e) return;
    const int rows = min(128, n_e - m0);

    const int tid = threadIdx.x;
    if (tid < 128) {
        tokS[tid] = (e == E_NUM) ? (m0 + tid)
                  : ((tid < rows) ? tok_list[e * T_TOK + m0 + tid]
                                  : tok_list[e * T_TOK + m0]);
    }
    __syncthreads();

    // staging descriptors
    const unsigned short* aSrc[4]; unsigned short* aDst[4];
    #pragma unroll
    for (int j = 0; j < 4; j++) {
        int u = tid + j * 256;
        int r = u >> 3, ch = u & 7;
        aSrc[j] = xb + (size_t)tokS[r] * H_DIM + ch * 8;
        aDst[j] = &As[r * 72 + ch * 8];
    }
    const float* bSrc[8]; unsigned short* bDst[8];
    #pragma unroll
    for (int j = 0; j < 8; j++) {
        int u = tid + j * 256;
        int r = u >> 4, c4 = u & 15;
        int gr = nb * 64 + (r & 63) + ((r >> 6) ? I_DIM : 0);
        bSrc[j] = Bp + (size_t)gr * H_DIM + c4 * 4;
        bDst[j] = &Bs[r * 72 + c4 * 4];
    }

    const int wave = tid >> 6;
    const int lane = tid & 63;
    const int ln = lane & 15;
    const int kq = lane >> 4;

    f32x4 acc[2][8];
    #pragma unroll
    for (int a = 0; a < 2; a++)
        #pragma unroll
        for (int b = 0; b < 8; b++) acc[a][b] = (f32x4){0.f, 0.f, 0.f, 0.f};

    for (int k0 = 0; k0 < H_DIM; k0 += 64) {
        __syncthreads();
        #pragma unroll
        for (int j = 0; j < 4; j++)
            *(int4*)aDst[j] = *(const int4*)(aSrc[j] + k0);
        #pragma unroll
        for (int j = 0; j < 8; j++) {
            float4 v = *(const float4*)(bSrc[j] + k0);
            ushort4 o;
            o.x = f2bf(v.x); o.y = f2bf(v.y); o.z = f2bf(v.z); o.w = f2bf(v.w);
            *(ushort4*)bDst[j] = o;
        }
        __syncthreads();
        #pragma unroll
        for (int ks = 0; ks < 2; ks++) {
            bf16x8 af[2];
            #pragma unroll
            for (int mt = 0; mt < 2; mt++)
                af[mt] = *(const bf16x8*)(&As[(wave * 32 + mt * 16 + ln) * 72 + ks * 32 + kq * 8]);
            #pragma unroll
            for (int j = 0; j < 8; j++) {
                bf16x8 bfr = *(const bf16x8*)(&Bs[(j * 16 + ln) * 72 + ks * 32 + kq * 8]);
                #pragma unroll
                for (int mt = 0; mt < 2; mt++)
                    acc[mt][j] = __builtin_amdgcn_mfma_f32_16x16x32_bf16(af[mt], bfr, acc[mt][j], 0, 0, 0);
            }
        }
    }

    #pragma unroll
    for (int mt = 0; mt < 2; mt++) {
        #pragma unroll
        for (int j = 0; j < 4; j++) {
            f32x4 g = acc[mt][j];
            f32x4 u = acc[mt][j + 4];
            int col = nb * 64 + j * 16 + ln;
            #pragma unroll
            for (int r = 0; r < 4; r++) {
                int rit = wave * 32 + mt * 16 + kq * 4 + r;
                if (rit < rows) {
                    float gv = g[r];
                    float sv = gv / (1.f + __expf(-gv)) * u[r];
                    act[(size_t)(rowbase + rit) * I_DIM + col] = f2bf(sv);
                }
            }
        }
    }
}

// ---------------- Grouped down GEMM + weighted scatter-add ----------------
__global__ __launch_bounds__(256, 2) void down_kernel(
    const unsigned short* __restrict__ act, const float* __restrict__ w_down,
    const float* __restrict__ shared_down, const int* __restrict__ cnt,
    const int* __restrict__ tok_list, const float* __restrict__ w_list,
    float* __restrict__ y)
{
    __shared__ unsigned short As[128 * 72];
    __shared__ unsigned short Bs[128 * 72];
    __shared__ int tokS[128];
    __shared__ float wS[128];

    const int nb = blockIdx.x;          // y cols [nb*128, +128)
    const int ey = blockIdx.y;
    const int e  = ey >> 3;
    const int m0 = (ey & 7) * 128;

    int n_e, rowbase;
    const float* Bp;
    if (e == E_NUM) { n_e = T_TOK; rowbase = 8192 + m0; Bp = shared_down; }
    else {
        n_e = cnt[e];
        int off = 0;
        for (int i = 0; i < e; i++) off += cnt[i];
        rowbase = off + m0;
        Bp = w_down + (size_t)e * H_DIM * I_DIM;
    }
    if (m0 >= n_e) return;
    const int rows = min(128, n_e - m0);

    const int tid = threadIdx.x;
    if (tid < 128) {
        if (e == E_NUM) { tokS[tid] = m0 + tid; wS[tid] = 1.f; }
        else if (tid < rows) {
            tokS[tid] = tok_list[e * T_TOK + m0 + tid];
            wS[tid]   = w_list[e * T_TOK + m0 + tid];
        } else { tokS[tid] = 0; wS[tid] = 0.f; }
    }
    __syncthreads();

    const unsigned short* aSrc[4]; unsigned short* aDst[4];
    #pragma unroll
    for (int j = 0; j < 4; j++) {
        int u = tid + j * 256;
        int r = u >> 3, ch = u & 7;
        aSrc[j] = act + (size_t)(rowbase + r) * I_DIM + ch * 8;
        aDst[j] = &As[r * 72 + ch * 8];
    }
    const float* bSrc[8]; unsigned short* bDst[8];
    #pragma unroll
    for (int j = 0; j < 8; j++) {
        int u = tid + j * 256;
        int r = u >> 4, c4 = u & 15;
        bSrc[j] = Bp + (size_t)(nb * 128 + r) * I_DIM + c4 * 4;
        bDst[j] = &Bs[r * 72 + c4 * 4];
    }

    const int wave = tid >> 6;
    const int lane = tid & 63;
    const int ln = lane & 15;
    const int kq = lane >> 4;

    f32x4 acc[2][8];
    #pragma unroll
    for (int a = 0; a < 2; a++)
        #pragma unroll
        for (int b = 0; b < 8; b++) acc[a][b] = (f32x4){0.f, 0.f, 0.f, 0.f};

    for (int k0 = 0; k0 < I_DIM; k0 += 64) {
        __syncthreads();
        #pragma unroll
        for (int j = 0; j < 4; j++)
            *(int4*)aDst[j] = *(const int4*)(aSrc[j] + k0);
        #pragma unroll
        for (int j = 0; j < 8; j++) {
            float4 v = *(const float4*)(bSrc[j] + k0);
            ushort4 o;
            o.x = f2bf(v.x); o.y = f2bf(v.y); o.z = f2bf(v.z); o.w = f2bf(v.w);
            *(ushort4*)bDst[j] = o;
        }
        __syncthreads();
        #pragma unroll
        for (int ks = 0; ks < 2; ks++) {
            bf16x8 af[2];
            #pragma unroll
            for (int mt = 0; mt < 2; mt++)
                af[mt] = *(const bf16x8*)(&As[(wave * 32 + mt * 16 + ln) * 72 + ks * 32 + kq * 8]);
            #pragma unroll
            for (int j = 0; j < 8; j++) {
                bf16x8 bfr = *(const bf16x8*)(&Bs[(j * 16 + ln) * 72 + ks * 32 + kq * 8]);
                #pragma unroll
                for (int mt = 0; mt < 2; mt++)
                    acc[mt][j] = __builtin_amdgcn_mfma_f32_16x16x32_bf16(af[mt], bfr, acc[mt][j], 0, 0, 0);
            }
        }
    }

    #pragma unroll
    for (int mt = 0; mt < 2; mt++) {
        #pragma unroll
        for (int j = 0; j < 8; j++) {
            int col = nb * 128 + j * 16 + ln;
            #pragma unroll
            for (int r = 0; r < 4; r++) {
                int rit = wave * 32 + mt * 16 + kq * 4 + r;
                if (rit < rows) {
                    atomicAdd(&y[(size_t)tokS[rit] * H_DIM + col], acc[mt][j][r] * wS[rit]);
                }
            }
        }
    }
}

extern "C" void kernel_launch(void* const* d_in, const int* in_sizes, int n_in,
                              void* d_out, int out_size, void* d_ws, size_t ws_size,
                              hipStream_t stream) {
    const float* x       = (const float*)d_in[0];
    const float* gate_w  = (const float*)d_in[1];
    const float* bias    = (const float*)d_in[2];
    const float* w_gu    = (const float*)d_in[3];
    const float* w_dn    = (const float*)d_in[4];
    const float* sh_gu   = (const float*)d_in[5];
    const float* sh_dn   = (const float*)d_in[6];
    float* y = (float*)d_out;

    char* ws = (char*)d_ws;
    int*   cnt      = (int*)ws;                                   // 32 ints
    int*   tok_list = (int*)(ws + 1024);                          // 32*1024 ints
    float* w_list   = (float*)(ws + 1024 + 131072);               // 32*1024 floats
    unsigned short* xb  = (unsigned short*)(ws + 1024 + 262144);  // 1024*2048 bf16 (4MB)
    unsigned short* act = (unsigned short*)(ws + 1024 + 262144 + 4194304); // 9216*1024 bf16

    hipMemsetAsync(cnt, 0, 128, stream);
    hipMemsetAsync(y, 0, (size_t)out_size * sizeof(float), stream);

    router_kernel<<<T_TOK, 256, 0, stream>>>(x, gate_w, bias, cnt, tok_list, w_list);
    cvt_kernel<<<(T_TOK * H_DIM / 4) / 256, 256, 0, stream>>>(x, xb);
    gate_up_kernel<<<dim3(16, (E_NUM + 1) * 8), 256, 0, stream>>>(xb, w_gu, sh_gu, cnt, tok_list, act);
    down_kernel<<<dim3(16, (E_NUM + 1) * 8), 256, 0, stream>>>(act, w_dn, sh_dn, cnt, tok_list, w_list, y);
}

// Round 2
// 1372.257 us; speedup vs baseline: 1.0477x; 1.0477x over previous
//
#include <hip/hip_runtime.h>
#include <math.h>

#define T_TOK 1024
#define H_DIM 2048
#define I_DIM 1024
#define E_NUM 32
#define G_NUM 8
#define EPG (E_NUM / G_NUM)
#define TOPK_GROUP 4
#define TOP_K 8
#define ROUTED_SCALE 2.5f

typedef __attribute__((ext_vector_type(8))) short bf16x8;
typedef __attribute__((ext_vector_type(4))) float f32x4;

__device__ __forceinline__ unsigned short f2bf(float f) {
    union { float f; unsigned u; } v; v.f = f;
    unsigned r = v.u + 0x7fffu + ((v.u >> 16) & 1u);   // RNE
    return (unsigned short)(r >> 16);
}

// ---------------- Router: fp32 logits, sigmoid, group-limited top-k ----------------
__global__ __launch_bounds__(256) void router_kernel(
    const float* __restrict__ x, const float* __restrict__ gate_w,
    const float* __restrict__ bias, int* __restrict__ cnt,
    int* __restrict__ tok_list, float* __restrict__ w_list)
{
    __shared__ float xs[H_DIM];
    __shared__ float part[E_NUM][8];
    __shared__ float scores[E_NUM];
    const int t = blockIdx.x;
    const int tid = threadIdx.x;

    const float4* xv = (const float4*)(x + (size_t)t * H_DIM);
    float4* xsv = (float4*)xs;
    for (int i = tid; i < H_DIM / 4; i += 256) xsv[i] = xv[i];
    __syncthreads();

    const int e = tid >> 3;      // 32 experts
    const int c = tid & 7;       // 8 lanes per expert
    const float4* gw4 = (const float4*)(gate_w + (size_t)e * H_DIM);
    const float4* xs4 = (const float4*)xs;
    float s = 0.f;
    #pragma unroll 8
    for (int j = 0; j < 64; j++) {
        float4 a = xs4[j * 8 + c];
        float4 b = gw4[j * 8 + c];
        s += a.x * b.x + a.y * b.y + a.z * b.z + a.w * b.w;
    }
    part[e][c] = s;
    __syncthreads();
    if (tid < E_NUM) {
        float l = 0.f;
        #pragma unroll
        for (int i = 0; i < 8; i++) l += part[tid][i];
        scores[tid] = 1.f / (1.f + expf(-l));
    }
    __syncthreads();
    if (tid == 0) {
        float sr[E_NUM];
        for (int i = 0; i < E_NUM; i++) sr[i] = scores[i] + bias[i];
        float gs[G_NUM];
        for (int g = 0; g < G_NUM; g++) {
            float m1 = -INFINITY, m2 = -INFINITY;
            for (int j = 0; j < EPG; j++) {
                float v = sr[g * EPG + j];
                if (v > m1) { m2 = m1; m1 = v; } else if (v > m2) { m2 = v; }
            }
            gs[g] = m1 + m2;
        }
        bool gmask[G_NUM];
        for (int g = 0; g < G_NUM; g++) gmask[g] = false;
        for (int k = 0; k < TOPK_GROUP; k++) {
            int bi = -1; float bv = -INFINITY;
            for (int g = 0; g < G_NUM; g++)
                if (!gmask[g] && gs[g] > bv) { bv = gs[g]; bi = g; }
            gmask[bi] = true;
        }
        bool esel[E_NUM];
        for (int i = 0; i < E_NUM; i++) esel[i] = false;
        int ids[TOP_K]; float wv[TOP_K]; float wsum = 0.f;
        for (int k = 0; k < TOP_K; k++) {
            int bi = -1; float bv = -INFINITY;
            for (int i = 0; i < E_NUM; i++) {
                if (esel[i] || !gmask[i / EPG]) continue;
                if (sr[i] > bv) { bv = sr[i]; bi = i; }
            }
            esel[bi] = true; ids[k] = bi;
            wv[k] = scores[bi]; wsum += wv[k];
        }
        const float scale = ROUTED_SCALE / (wsum + 1e-20f);
        for (int k = 0; k < TOP_K; k++) {
            int ei = ids[k];
            int slot = atomicAdd(&cnt[ei], 1);
            tok_list[ei * T_TOK + slot] = t;
            w_list[ei * T_TOK + slot] = wv[k] * scale;
        }
    }
}

// ---------------- x -> bf16 ----------------
__global__ __launch_bounds__(256) void cvt_kernel(const float* __restrict__ x,
                                                  unsigned short* __restrict__ xb)
{
    int i = blockIdx.x * 256 + threadIdx.x;
    float4 v = ((const float4*)x)[i];
    ushort4 o;
    o.x = f2bf(v.x); o.y = f2bf(v.y); o.z = f2bf(v.z); o.w = f2bf(v.w);
    ((ushort4*)xb)[i] = o;
}

// ---------------- Grouped gate_up GEMM + SiLU*u epilogue (pipelined) ----------------
__global__ __launch_bounds__(256, 2) void gate_up_kernel(
    const unsigned short* __restrict__ xb, const float* __restrict__ w_gate_up,
    const float* __restrict__ shared_gate_up, const int* __restrict__ cnt,
    const int* __restrict__ tok_list, unsigned short* __restrict__ act)
{
    __shared__ unsigned short As[128 * 72];
    __shared__ unsigned short Bs[128 * 72];
    __shared__ int tokS[128];

    const int nb = blockIdx.x;
    const int ey = blockIdx.y;
    const int e  = ey >> 3;
    const int m0 = (ey & 7) * 128;

    int n_e, rowbase;
    const float* Bp;
    if (e == E_NUM) { n_e = T_TOK; rowbase = 8192 + m0; Bp = shared_gate_up; }
    else {
        n_e = cnt[e];
        int off = 0;
        for (int i = 0; i < e; i++) off += cnt[i];
        rowbase = off + m0;
        Bp = w_gate_up + (size_t)e * (2 * I_DIM) * H_DIM;
    }
    if (m0 >= n_e) return;
    const int rows = min(128, n_e - m0);

    const int tid = threadIdx.x;
    if (tid < 128) {
        tokS[tid] = (e == E_NUM) ? (m0 + tid)
                  : ((tid < rows) ? tok_list[e * T_TOK + m0 + tid]
                                  : tok_list[e * T_TOK + m0]);
    }
    __syncthreads();

    const unsigned short* aSrc[4]; unsigned short* aDst[4];
    #pragma unroll
    for (int j = 0; j < 4; j++) {
        int u = tid + j * 256;
        int r = u >> 3, ch = u & 7;
        aSrc[j] = xb + (size_t)tokS[r] * H_DIM + ch * 8;
        aDst[j] = &As[r * 72 + ch * 8];
    }
    const float* bSrc[8]; unsigned short* bDst[8];
    #pragma unroll
    for (int j = 0; j < 8; j++) {
        int u = tid + j * 256;
        int r = u >> 4, c4 = u & 15;
        int gr = nb * 64 + (r & 63) + ((r >> 6) ? I_DIM : 0);
        bSrc[j] = Bp + (size_t)gr * H_DIM + c4 * 4;
        bDst[j] = &Bs[r * 72 + c4 * 4];
    }

    const int wave = tid >> 6;
    const int lane = tid & 63;
    const int ln = lane & 15;
    const int kq = lane >> 4;

    f32x4 acc[2][8];
    #pragma unroll
    for (int a = 0; a < 2; a++)
        #pragma unroll
        for (int b = 0; b < 8; b++) acc[a][b] = (f32x4){0.f, 0.f, 0.f, 0.f};

    // --- software pipeline: tile k0 lives in regs before it is stored to LDS ---
    int4   aReg[4];
    float4 bReg[8];
    #pragma unroll
    for (int j = 0; j < 4; j++) aReg[j] = *(const int4*)(aSrc[j]);
    #pragma unroll
    for (int j = 0; j < 8; j++) bReg[j] = *(const float4*)(bSrc[j]);

    for (int k0 = 0; k0 < H_DIM; k0 += 64) {
        __syncthreads();            // prev MFMA done reading LDS
        #pragma unroll
        for (int j = 0; j < 4; j++) *(int4*)aDst[j] = aReg[j];
        #pragma unroll
        for (int j = 0; j < 8; j++) {
            float4 v = bReg[j];
            ushort4 o;
            o.x = f2bf(v.x); o.y = f2bf(v.y); o.z = f2bf(v.z); o.w = f2bf(v.w);
            *(ushort4*)bDst[j] = o;
        }
        __syncthreads();
        // prefetch next tile — loads in flight during MFMA below
        const int kn = k0 + 64;
        if (kn < H_DIM) {
            #pragma unroll
            for (int j = 0; j < 4; j++) aReg[j] = *(const int4*)(aSrc[j] + kn);
            #pragma unroll
            for (int j = 0; j < 8; j++) bReg[j] = *(const float4*)(bSrc[j] + kn);
        }
        #pragma unroll
        for (int ks = 0; ks < 2; ks++) {
            bf16x8 af[2];
            #pragma unroll
            for (int mt = 0; mt < 2; mt++)
                af[mt] = *(const bf16x8*)(&As[(wave * 32 + mt * 16 + ln) * 72 + ks * 32 + kq * 8]);
            #pragma unroll
            for (int j = 0; j < 8; j++) {
                bf16x8 bfr = *(const bf16x8*)(&Bs[(j * 16 + ln) * 72 + ks * 32 + kq * 8]);
                #pragma unroll
                for (int mt = 0; mt < 2; mt++)
                    acc[mt][j] = __builtin_amdgcn_mfma_f32_16x16x32_bf16(af[mt], bfr, acc[mt][j], 0, 0, 0);
            }
        }
    }

    #pragma unroll
    for (int mt = 0; mt < 2; mt++) {
        #pragma unroll
        for (int j = 0; j < 4; j++) {
            f32x4 g = acc[mt][j];
            f32x4 u = acc[mt][j + 4];
            int col = nb * 64 + j * 16 + ln;
            #pragma unroll
            for (int r = 0; r < 4; r++) {
                int rit = wave * 32 + mt * 16 + kq * 4 + r;
                if (rit < rows) {
                    float gv = g[r];
                    float sv = gv / (1.f + __expf(-gv)) * u[r];
                    act[(size_t)(rowbase + rit) * I_DIM + col] = f2bf(sv);
                }
            }
        }
    }
}

// ---------------- Grouped down GEMM + weighted scatter-add (pipelined) ----------------
__global__ __launch_bounds__(256, 2) void down_kernel(
    const unsigned short* __restrict__ act, const float* __restrict__ w_down,
    const float* __restrict__ shared_down, const int* __restrict__ cnt,
    const int* __restrict__ tok_list, const float* __restrict__ w_list,
    float* __restrict__ y)
{
    __shared__ unsigned short As[128 * 72];
    __shared__ unsigned short Bs[128 * 72];
    __shared__ int tokS[128];
    __shared__ float wS[128];

    const int nb = blockIdx.x;
    const int ey = blockIdx.y;
    const int e  = ey >> 3;
    const int m0 = (ey & 7) * 128;

    int n_e, rowbase;
    const float* Bp;
    if (e == E_NUM) { n_e = T_TOK; rowbase = 8192 + m0; Bp = shared_down; }
    else {
        n_e = cnt[e];
        int off = 0;
        for (int i = 0; i < e; i++) off += cnt[i];
        rowbase = off + m0;
        Bp = w_down + (size_t)e * H_DIM * I_DIM;
    }
    if (m0 >= n_e) return;
    const int rows = min(128, n_e - m0);

    const int tid = threadIdx.x;
    if (tid < 128) {
        if (e == E_NUM) { tokS[tid] = m0 + tid; wS[tid] = 1.f; }
        else if (tid < rows) {
            tokS[tid] = tok_list[e * T_TOK + m0 + tid];
            wS[tid]   = w_list[e * T_TOK + m0 + tid];
        } else { tokS[tid] = 0; wS[tid] = 0.f; }
    }
    __syncthreads();

    const unsigned short* aSrc[4]; unsigned short* aDst[4];
    #pragma unroll
    for (int j = 0; j < 4; j++) {
        int u = tid + j * 256;
        int r = u >> 3, ch = u & 7;
        aSrc[j] = act + (size_t)(rowbase + r) * I_DIM + ch * 8;
        aDst[j] = &As[r * 72 + ch * 8];
    }
    const float* bSrc[8]; unsigned short* bDst[8];
    #pragma unroll
    for (int j = 0; j < 8; j++) {
        int u = tid + j * 256;
        int r = u >> 4, c4 = u & 15;
        bSrc[j] = Bp + (size_t)(nb * 128 + r) * I_DIM + c4 * 4;
        bDst[j] = &Bs[r * 72 + c4 * 4];
    }

    const int wave = tid >> 6;
    const int lane = tid & 63;
    const int ln = lane & 15;
    const int kq = lane >> 4;

    f32x4 acc[2][8];
    #pragma unroll
    for (int a = 0; a < 2; a++)
        #pragma unroll
        for (int b = 0; b < 8; b++) acc[a][b] = (f32x4){0.f, 0.f, 0.f, 0.f};

    int4   aReg[4];
    float4 bReg[8];
    #pragma unroll
    for (int j = 0; j < 4; j++) aReg[j] = *(const int4*)(aSrc[j]);
    #pragma unroll
    for (int j = 0; j < 8; j++) bReg[j] = *(const float4*)(bSrc[j]);

    for (int k0 = 0; k0 < I_DIM; k0 += 64) {
        __syncthreads();
        #pragma unroll
        for (int j = 0; j < 4; j++) *(int4*)aDst[j] = aReg[j];
        #pragma unroll
        for (int j = 0; j < 8; j++) {
            float4 v = bReg[j];
            ushort4 o;
            o.x = f2bf(v.x); o.y = f2bf(v.y); o.z = f2bf(v.z); o.w = f2bf(v.w);
            *(ushort4*)bDst[j] = o;
        }
        __syncthreads();
        const int kn = k0 + 64;
        if (kn < I_DIM) {
            #pragma unroll
            for (int j = 0; j < 4; j++) aReg[j] = *(const int4*)(aSrc[j] + kn);
            #pragma unroll
            for (int j = 0; j < 8; j++) bReg[j] = *(const float4*)(bSrc[j] + kn);
        }
        #pragma unroll
        for (int ks = 0; ks < 2; ks++) {
            bf16x8 af[2];
            #pragma unroll
            for (int mt = 0; mt < 2; mt++)
                af[mt] = *(const bf16x8*)(&As[(wave * 32 + mt * 16 + ln) * 72 + ks * 32 + kq * 8]);
            #pragma unroll
            for (int j = 0; j < 8; j++) {
                bf16x8 bfr = *(const bf16x8*)(&Bs[(j * 16 + ln) * 72 + ks * 32 + kq * 8]);
                #pragma unroll
                for (int mt = 0; mt < 2; mt++)
                    acc[mt][j] = __builtin_amdgcn_mfma_f32_16x16x32_bf16(af[mt], bfr, acc[mt][j], 0, 0, 0);
            }
        }
    }

    #pragma unroll
    for (int mt = 0; mt < 2; mt++) {
        #pragma unroll
        for (int j = 0; j < 8; j++) {
            int col = nb * 128 + j * 16 + ln;
            #pragma unroll
            for (int r = 0; r < 4; r++) {
                int rit = wave * 32 + mt * 16 + kq * 4 + r;
                if (rit < rows) {
                    atomicAdd(&y[(size_t)tokS[rit] * H_DIM + col], acc[mt][j][r] * wS[rit]);
                }
            }
        }
    }
}

extern "C" void kernel_launch(void* const* d_in, const int* in_sizes, int n_in,
                              void* d_out, int out_size, void* d_ws, size_t ws_size,
                              hipStream_t stream) {
    const float* x       = (const float*)d_in[0];
    const float* gate_w  = (const float*)d_in[1];
    const float* bias    = (const float*)d_in[2];
    const float* w_gu    = (const float*)d_in[3];
    const float* w_dn    = (const float*)d_in[4];
    const float* sh_gu   = (const float*)d_in[5];
    const float* sh_dn   = (const float*)d_in[6];
    float* y = (float*)d_out;

    char* ws = (char*)d_ws;
    int*   cnt      = (int*)ws;
    int*   tok_list = (int*)(ws + 1024);
    float* w_list   = (float*)(ws + 1024 + 131072);
    unsigned short* xb  = (unsigned short*)(ws + 1024 + 262144);
    unsigned short* act = (unsigned short*)(ws + 1024 + 262144 + 4194304);

    hipMemsetAsync(cnt, 0, 128, stream);
    hipMemsetAsync(y, 0, (size_t)out_size * sizeof(float), stream);

    router_kernel<<<T_TOK, 256, 0, stream>>>(x, gate_w, bias, cnt, tok_list, w_list);
    cvt_kernel<<<(T_TOK * H_DIM / 4) / 256, 256, 0, stream>>>(x, xb);
    gate_up_kernel<<<dim3(16, (E_NUM + 1) * 8), 256, 0, stream>>>(xb, w_gu, sh_gu, cnt, tok_list, act);
    down_kernel<<<dim3(16, (E_NUM + 1) * 8), 256, 0, stream>>>(act, w_dn, sh_dn, cnt, tok_list, w_list, y);
}